// Round 16
// baseline (1046.306 us; speedup 1.0000x reference)
//
#include <hip/hip_runtime.h>
#include <stdint.h>

// VQ-VAE nearest-codebook index: N=32768 queries, D=64, K=8192 codes.
// Phase A: bf16x3 MFMA (hi/lo split), argmax form (C-init = -0.5*||c||^2),
//          med3 second-best tracking, B direct L2->registers (LDS-free,
//          barrier-free; 1-step reg prefetch). 32 q/wave, 128 q/block.
//          Split-K=8 grid (2048 blocks).
// R19 post-mortem: occupancy stayed ~39% despite grid=8 blocks/CU, LDS=0,
//          VGPR=60. Explanation consistent with ALL session data: gfx950
//          unified register file -- waves/SIMD = 512/(VGPR + AGPR); the
//          compiler's AGPR allocation (~32-64 for MFMA accs, not shown in
//          the counter CSV) makes total ~124/wave => 4 waves/SIMD.
//          (R18's (256,8): budget 64 total => 32V+32A + spill storm.)
// R20: __launch_bounds__(256, 6) -- budget 85 total regs. Natural need
//          ~60 arch + ~24-32 AGPR fits with light rematerialization =>
//          6 waves/SIMD (+50% TLP, the only lever that ever moved this
//          kernel). Health check: WRITE_SIZE must stay ~3 MB (no spill).
// Tail: fused merge(NP partials) + pruned exact re-solve + write.
//          EPS 0.008 > 2*delta = 6.2e-3 worst-case bf16x3 bound;
//          flag-and-repair validated absmax=0 across R6-R19.

#define N_TOTAL 32768
#define K_CODES 8192
#define EPS_GAP 0.008f

typedef __attribute__((ext_vector_type(4)))  float  floatx4;
typedef __attribute__((ext_vector_type(8)))  __bf16 bf16x8;

// ---- workspace layouts (bytes) ----
#define O_C2    0u          // 8192 f32
#define O_CBSW  32768u      // [256 kBlk][16 g][32 m][8 bf16] = 2 MB
// split-4 (legacy) partials:
#define O4_PS1  2129920u    // 4*32768 f32
#define O4_PS2  2654208u
#define O4_PI1  3178496u
#define WS_NEED4 4096256u
// split-8 partials:
#define O8_PS1  2129920u    // 8*32768 f32 = 1 MB
#define O8_PS2  3178496u
#define O8_PI1  4227072u
#define WS_NEED8 5275648u

__device__ __forceinline__ void load_lds16(const void* g, void* l) {
    __builtin_amdgcn_global_load_lds(
        (const __attribute__((address_space(1))) unsigned int*)g,
        (__attribute__((address_space(3))) unsigned int*)l, 16, 0, 0);
}

// ---- prep: split codebook into hi/lo bf16 fragments + row norms ----
// cbSw layout: [kBlk(32 codes)][g 0..7=hi dims g*8..g*8+7, 8..15=lo][m 0..31]
__global__ __launch_bounds__(256) void vq_prep(
    const float4* __restrict__ cb, uint4* __restrict__ cbSw,
    float* __restrict__ c2) {
    __shared__ float red[256];
    const int m = threadIdx.x & 31, g = threadIdx.x >> 5;
    const int rb = blockIdx.x;
    float4 a = cb[(size_t)(rb * 32 + m) * 16 + g * 2];
    float4 b = cb[(size_t)(rb * 32 + m) * 16 + g * 2 + 1];
    float x[8] = {a.x, a.y, a.z, a.w, b.x, b.y, b.z, b.w};
    bf16x8 hv, lv;
    float ss = 0.f;
#pragma unroll
    for (int i = 0; i < 8; ++i) {
        float v  = x[i];
        __bf16 hb = (__bf16)v;           // RNE
        float r  = v - (float)hb;
        hv[i] = hb;
        lv[i] = (__bf16)r;
        ss += v * v;
    }
    cbSw[(size_t)rb * 512 + g * 32 + m]       = __builtin_bit_cast(uint4, hv);
    cbSw[(size_t)rb * 512 + (8 + g) * 32 + m] = __builtin_bit_cast(uint4, lv);
    red[threadIdx.x] = ss;
    __syncthreads();
    if (threadIdx.x < 32) {
        float s = 0.f;
#pragma unroll
        for (int gg = 0; gg < 8; ++gg) s += red[threadIdx.x + 32 * gg];
        c2[rb * 32 + threadIdx.x] = s;
    }
}

// ---- phase A: 128 queries x (8192/NP) codes per block (split-K=NP) ----
// 16x16x32 MFMA. Wave: 32 queries (2 q-tiles). KP/16 flat steps; per step
// one 16-code col-tile: 4 B-frag uint4 loads (L2->reg) + 12 MFMA + track.
// C/D: col=lane&15, row=(lane>>4)*4+reg  [verified absmax=0, R10-R19].
// launch_bounds (256,6): unified-file budget 85 regs/wave -> 6 waves/SIMD.
template <int NP>
__global__ __launch_bounds__(256, 6) void vq_mfma(
    const float4* __restrict__ lat, const uint4* __restrict__ cbSw,
    const float* __restrict__ c2,
    float* __restrict__ pS1, float* __restrict__ pS2, int* __restrict__ pI1) {
    constexpr int KP = K_CODES / NP;
    constexpr int STEPS = KP / 16;
    const int tid = threadIdx.x;
    const int wr = tid >> 6, lane = tid & 63;
    const int c16 = lane & 15, h4 = lane >> 4;

    // A fragments for 2 q-tiles (split in-kernel; identical math to vq_prep).
    const int q0 = blockIdx.x * 128 + wr * 32 + c16;
    bf16x8 aH[2][2], aL[2][2];
#pragma unroll
    for (int qt = 0; qt < 2; ++qt)
#pragma unroll
    for (int c = 0; c < 2; ++c) {
        float4 v0 = lat[(size_t)(q0 + qt * 16) * 16 + c * 8 + h4 * 2];
        float4 v1 = lat[(size_t)(q0 + qt * 16) * 16 + c * 8 + h4 * 2 + 1];
        float x[8] = {v0.x, v0.y, v0.z, v0.w, v1.x, v1.y, v1.z, v1.w};
#pragma unroll
        for (int j = 0; j < 8; ++j) {
            float v  = x[j];
            __bf16 hb = (__bf16)v;
            aH[qt][c][j] = hb;
            aL[qt][c][j] = (__bf16)(v - (float)hb);
        }
    }

    // Track t1 = max(-s/2), t2 = second-max, i1 = argmax, per (qt, row).
    float t1[2][4], t2[2][4]; int i1[2][4];
#pragma unroll
    for (int qt = 0; qt < 2; ++qt)
#pragma unroll
    for (int r = 0; r < 4; ++r) { t1[qt][r] = -3e38f; t2[qt][r] = -3e38f; i1[qt][r] = 0; }

    const int kBase = blockIdx.y * KP;
    const uint4* sB = cbSw + ((size_t)(kBase >> 5) << 9);  // partition base
    const float* c2g = c2 + kBase + c16;   // per-lane c2 stream base
    const int fb = c16 + h4 * 32;          // frag offset within a step group

    // step s: stage = s>>2, T = s&3. uint4 group offset:
    //   off(s) = (s>>2)*1024 + (s&2)*256 + (s&1)*16
    // members at off+fb, +128, +256, +384 (bH0,bH1,bL0,bL1).
    // c2 scalar at c2g[(s>>2)*64 + (s&3)*16].

    // ---- prologue: load step-0 group ----
    uint4 b0, b1, b2, b3;
    {
        const uint4* p = sB + fb;
        b0 = p[0]; b1 = p[128]; b2 = p[256]; b3 = p[384];
    }
    float ccCur = c2g[0];

#pragma unroll 2
    for (int step = 0; step < STEPS; ++step) {
        // prefetch step+1 group (tail clamped: uniform pipeline, no branch)
        const int s1 = (step + 1 < STEPS) ? (step + 1) : (STEPS - 1);
        const uint4* p = sB + ((s1 >> 2) << 10) + ((s1 & 2) << 8) + ((s1 & 1) << 4) + fb;
        uint4 n0 = p[0], n1 = p[128], n2 = p[256], n3 = p[384];
        float ccN = c2g[((s1 >> 2) << 6) + ((s1 & 3) << 4)];

        const int col = kBase + ((step >> 2) << 6) + ((step & 3) << 4) + c16;
        const float nn = -0.5f * ccCur;   // prefetched last step: no chain-head stall
        bf16x8 bH0 = __builtin_bit_cast(bf16x8, b0);
        bf16x8 bH1 = __builtin_bit_cast(bf16x8, b1);
        bf16x8 bL0 = __builtin_bit_cast(bf16x8, b2);
        bf16x8 bL1 = __builtin_bit_cast(bf16x8, b3);

        __builtin_amdgcn_s_setprio(1);
        // 2 independent 6-MFMA chains (one per q-tile) sharing B regs.
#pragma unroll
        for (int qt = 0; qt < 2; ++qt) {
            floatx4 acc = {nn, nn, nn, nn};
            acc = __builtin_amdgcn_mfma_f32_16x16x32_bf16(aH[qt][0], bH0, acc, 0, 0, 0);
            acc = __builtin_amdgcn_mfma_f32_16x16x32_bf16(aH[qt][1], bH1, acc, 0, 0, 0);
            acc = __builtin_amdgcn_mfma_f32_16x16x32_bf16(aL[qt][0], bH0, acc, 0, 0, 0);
            acc = __builtin_amdgcn_mfma_f32_16x16x32_bf16(aL[qt][1], bH1, acc, 0, 0, 0);
            acc = __builtin_amdgcn_mfma_f32_16x16x32_bf16(aH[qt][0], bL0, acc, 0, 0, 0);
            acc = __builtin_amdgcn_mfma_f32_16x16x32_bf16(aH[qt][1], bL1, acc, 0, 0, 0);
            // acc[r] = dot - ||c||^2/2 = -s/2 : argmin(s) == argmax(acc).
#pragma unroll
            for (int r = 0; r < 4; ++r) {
                float a = acc[r];
                bool gt = a > t1[qt][r];
                t2[qt][r] = __builtin_amdgcn_fmed3f(a, t1[qt][r], t2[qt][r]);
                t1[qt][r] = fmaxf(t1[qt][r], a);
                i1[qt][r] = gt ? col : i1[qt][r];
            }
        }
        __builtin_amdgcn_s_setprio(0);

        b0 = n0; b1 = n1; b2 = n2; b3 = n3;   // unroll-2 renames these away
        ccCur = ccN;
    }

    // reduce (t1,i1,t2) across the 16 column-lanes of each row-group
#pragma unroll
    for (int mask = 1; mask <= 8; mask <<= 1) {
#pragma unroll
        for (int qt = 0; qt < 2; ++qt)
#pragma unroll
        for (int r = 0; r < 4; ++r) {
            float o1 = __shfl_xor(t1[qt][r], mask);
            float o2 = __shfl_xor(t2[qt][r], mask);
            int   oi = __shfl_xor(i1[qt][r], mask);
            float n2 = fmaxf(fmaxf(t2[qt][r], o2), fminf(t1[qt][r], o1));
            bool take = (o1 > t1[qt][r]) || (o1 == t1[qt][r] && oi < i1[qt][r]);
            t1[qt][r] = take ? o1 : t1[qt][r];
            i1[qt][r] = take ? oi : i1[qt][r];
            t2[qt][r] = n2;
        }
    }

    if (c16 == 0) {
        const int o0 = blockIdx.y * N_TOTAL;
#pragma unroll
        for (int qt = 0; qt < 2; ++qt) {
            const int qb = blockIdx.x * 128 + wr * 32 + qt * 16 + h4 * 4; // C/D rows
#pragma unroll
            for (int r = 0; r < 4; ++r) {
                pS1[o0 + qb + r] = -2.f * t1[qt][r];  // exact *2: order preserved
                pS2[o0 + qb + r] = -2.f * t2[qt][r];
                pI1[o0 + qb + r] = i1[qt][r];
            }
        }
    }
}

// ---- fused tail: merge NP partials + pruned exact re-solve + write ----
// Block owns 128 queries. Phase 1 (tid<128): merge, write provisional out,
// flag near-ties into LDS with a per-partition scan-mask. Phase 2: per
// flagged entry, all 256 threads cooperate -- scan partitions split
// KP/256 codes/thread; non-scan partitions' top-1 by threads 0..NP-1 --
// then LDS argmin-reduce (index tie-break) and direct out write.
template <int NP>
__global__ __launch_bounds__(256) void vq_tail(
    const float4* __restrict__ lat, const float* __restrict__ cbf,
    const float* __restrict__ c2,
    const float* __restrict__ pS1, const float* __restrict__ pS2,
    const int* __restrict__ pI1, int* __restrict__ out) {
    constexpr int KP = K_CODES / NP;
    __shared__ unsigned char fqv[132];   // local (in-block) flagged query ids
    __shared__ unsigned short fmk[132];  // scan masks (up to 8 bits)
    __shared__ int fcnt;
    __shared__ float qv[64];
    __shared__ float redS[256];
    __shared__ int   redI[256];

    const int tid = threadIdx.x;
    if (tid == 0) fcnt = 0;
    __syncthreads();

    if (tid < 128) {
        const int q = blockIdx.x * 128 + tid;
        float g1 = 3e38f, g2 = 3e38f;
        int   gi = 0x7FFFFFFF;
        float s2v[NP];
#pragma unroll
        for (int p = 0; p < NP; ++p) {
            float s1p = pS1[p * N_TOTAL + q];
            float s2p = pS2[p * N_TOTAL + q];
            int   i1p = pI1[p * N_TOTAL + q];
            s2v[p] = s2p;
            bool take = (s1p < g1) || (s1p == g1 && i1p < gi);
            g2 = fminf(g2, fminf(s2p, take ? g1 : s1p));
            if (take) { g1 = s1p; gi = i1p; }
        }
        out[q] = gi;
        if (g2 - g1 < EPS_GAP) {
            int msk = 0;
#pragma unroll
            for (int p = 0; p < NP; ++p)
                if (s2v[p] - g1 < EPS_GAP) msk |= (1 << p);
            int e = atomicAdd(&fcnt, 1);
            fqv[e] = (unsigned char)tid;
            fmk[e] = (unsigned short)msk;
        }
    }
    __syncthreads();

    const int ne = fcnt;
    for (int e = 0; e < ne; ++e) {
        const int lq = fqv[e];
        const int gq = blockIdx.x * 128 + lq;
        const int msk = fmk[e];
        if (tid < 16) {
            float4 v = lat[(size_t)gq * 16 + tid];
            *(float4*)&qv[tid * 4] = v;
        }
        __syncthreads();

        float best = 3e38f; int bi = 0x7FFFFFFF;
        // non-scan partitions: single-candidate exact eval by threads 0..NP-1
        if (tid < NP && !((msk >> tid) & 1)) {
            const int k = pI1[tid * N_TOTAL + gq];
            const float4* cp = (const float4*)&cbf[(size_t)k * 64];
            float dot = 0.f;
#pragma unroll
            for (int d4 = 0; d4 < 16; ++d4) {
                float4 cv = cp[d4];
                dot += qv[d4 * 4 + 0] * cv.x + qv[d4 * 4 + 1] * cv.y
                     + qv[d4 * 4 + 2] * cv.z + qv[d4 * 4 + 3] * cv.w;
            }
            float s = c2[k] - 2.f * dot;
            if (s < best || (s == best && k < bi)) { best = s; bi = k; }
        }
        // scan partitions: all 256 threads cooperate (KP/256 codes/thread)
#pragma unroll
        for (int p = 0; p < NP; ++p) if ((msk >> p) & 1) {
            for (int j = tid; j < KP; j += 256) {
                const int k = p * KP + j;
                const float4* cp = (const float4*)&cbf[(size_t)k * 64];
                float dot = 0.f;
#pragma unroll
                for (int d4 = 0; d4 < 16; ++d4) {
                    float4 cv = cp[d4];
                    dot += qv[d4 * 4 + 0] * cv.x + qv[d4 * 4 + 1] * cv.y
                         + qv[d4 * 4 + 2] * cv.z + qv[d4 * 4 + 3] * cv.w;
                }
                float s = c2[k] - 2.f * dot;
                if (s < best || (s == best && k < bi)) { best = s; bi = k; }
            }
        }
        // block argmin-reduce with index tie-break
        redS[tid] = best; redI[tid] = bi;
        __syncthreads();
        for (int s = 128; s > 0; s >>= 1) {
            if (tid < s) {
                float os = redS[tid + s]; int oi = redI[tid + s];
                if (os < redS[tid] || (os == redS[tid] && oi < redI[tid])) {
                    redS[tid] = os; redI[tid] = oi;
                }
            }
            __syncthreads();
        }
        if (tid == 0) out[gq] = redI[0];
        __syncthreads();   // protect qv/redS reuse next entry
    }
}

// ================= fallback: validated round-1 fp32 path =================
#define BM 128
#define BN 128
#define PAD 68

__global__ void vq_norms_fb(const float4* __restrict__ cb, float* __restrict__ c2) {
    int t = blockIdx.x * 256 + threadIdx.x;
    int r = t >> 2, p = t & 3;
    float s = 0.f;
#pragma unroll
    for (int i = 0; i < 4; ++i) {
        float4 v = cb[r * 16 + p * 4 + i];
        s += v.x * v.x + v.y * v.y + v.z * v.z + v.w * v.w;
    }
    s += __shfl_xor(s, 1);
    s += __shfl_xor(s, 2);
    if (p == 0) c2[r] = s;
}

__global__ __launch_bounds__(256) void vq_fp32(
    const float4* __restrict__ lat, const float4* __restrict__ cb,
    const float* __restrict__ c2, int ktPer,
    int* __restrict__ outIdx, float* __restrict__ partS, int* __restrict__ partI,
    int writePartial) {
    __shared__ float As[BM][PAD];
    __shared__ float Bsf[BN][PAD];
    __shared__ float c2s[BN];
    const int tid = threadIdx.x;
    const int tx = tid & 15;
    const int ty = tid >> 4;
    const int nBase = blockIdx.x * BM;
    const int kt0 = blockIdx.y * ktPer;
    const int ktN = kt0 + ktPer;
#pragma unroll
    for (int r = 0; r < 8; ++r) {
        int f = tid + 256 * r;
        int mm = f >> 4, d4 = f & 15;
        float4 v = lat[(size_t)(nBase + mm) * 16 + d4];
        *(float4*)&As[mm][d4 * 4] = v;
    }
    float best[8]; int bidx[8];
#pragma unroll
    for (int ii = 0; ii < 8; ++ii) { best[ii] = 3e38f; bidx[ii] = 0; }
    for (int kt = kt0; kt < ktN; ++kt) {
        const int kbase = kt * BN;
        __syncthreads();
#pragma unroll
        for (int r = 0; r < 8; ++r) {
            int f = tid + 256 * r;
            int k = f >> 4, d4 = f & 15;
            float4 v = cb[(size_t)(kbase + k) * 16 + d4];
            *(float4*)&Bsf[k][d4 * 4] = v;
        }
        if (tid < BN) c2s[tid] = c2[kbase + tid];
        __syncthreads();
        float acc[8][8];
#pragma unroll
        for (int ii = 0; ii < 8; ++ii)
#pragma unroll
            for (int jj = 0; jj < 8; ++jj) acc[ii][jj] = 0.f;
#pragma unroll 4
        for (int d4 = 0; d4 < 16; ++d4) {
            float4 a[8], b[8];
#pragma unroll
            for (int ii = 0; ii < 8; ++ii) a[ii] = *(const float4*)&As[tx + 16 * ii][d4 * 4];
#pragma unroll
            for (int jj = 0; jj < 8; ++jj) b[jj] = *(const float4*)&Bsf[ty + 16 * jj][d4 * 4];
#pragma unroll
            for (int ii = 0; ii < 8; ++ii)
#pragma unroll
                for (int jj = 0; jj < 8; ++jj)
                    acc[ii][jj] += a[ii].x * b[jj].x + a[ii].y * b[jj].y
                                 + a[ii].z * b[jj].z + a[ii].w * b[jj].w;
        }
#pragma unroll
        for (int jj = 0; jj < 8; ++jj) {
            int k = kbase + ty + 16 * jj;
            float cc = c2s[ty + 16 * jj];
#pragma unroll
            for (int ii = 0; ii < 8; ++ii) {
                float s = cc - 2.f * acc[ii][jj];
                if (s < best[ii]) { best[ii] = s; bidx[ii] = k; }
            }
        }
    }
    __syncthreads();
    float* redS = &As[0][0];
    int*   redI = (int*)&Bsf[0][0];
#pragma unroll
    for (int ii = 0; ii < 8; ++ii) {
        int mm = tx + 16 * ii;
        redS[ty * BM + mm] = best[ii];
        redI[ty * BM + mm] = bidx[ii];
    }
    __syncthreads();
    if (tid < BM) {
        int mm = tid;
        float bs = redS[mm]; int bi = redI[mm];
#pragma unroll
        for (int t = 1; t < 16; ++t) {
            float s = redS[t * BM + mm]; int i = redI[t * BM + mm];
            if (s < bs || (s == bs && i < bi)) { bs = s; bi = i; }
        }
        int n = nBase + mm;
        if (writePartial) { partS[blockIdx.y * N_TOTAL + n] = bs; partI[blockIdx.y * N_TOTAL + n] = bi; }
        else outIdx[n] = bi;
    }
}

__global__ void vq_merge_fb(const float* __restrict__ partS, const int* __restrict__ partI,
                            int* __restrict__ out) {
    int n = blockIdx.x * 256 + threadIdx.x;
    float s0 = partS[n], s1 = partS[N_TOTAL + n];
    int   i0 = partI[n], i1 = partI[N_TOTAL + n];
    out[n] = (s1 < s0) ? i1 : i0;
}

extern "C" void kernel_launch(void* const* d_in, const int* in_sizes, int n_in,
                              void* d_out, int out_size, void* d_ws, size_t ws_size,
                              hipStream_t stream) {
    const float4* lat = (const float4*)d_in[0];
    const float4* cb  = (const float4*)d_in[1];
    int* out = (int*)d_out;
    char* ws = (char*)d_ws;

    if (ws_size >= WS_NEED8) {
        float* c2   = (float*)(ws + O_C2);
        uint4* cbSw = (uint4*)(ws + O_CBSW);
        float* pS1  = (float*)(ws + O8_PS1);
        float* pS2  = (float*)(ws + O8_PS2);
        int*   pI1  = (int*)(ws + O8_PI1);

        vq_prep<<<256, 256, 0, stream>>>(cb, cbSw, c2);
        vq_mfma<8><<<dim3(256, 8), 256, 0, stream>>>(lat, cbSw, c2, pS1, pS2, pI1);
        vq_tail<8><<<256, 256, 0, stream>>>(lat, (const float*)cb, c2, pS1, pS2, pI1, out);
    } else if (ws_size >= WS_NEED4) {
        float* c2   = (float*)(ws + O_C2);
        uint4* cbSw = (uint4*)(ws + O_CBSW);
        float* pS1  = (float*)(ws + O4_PS1);
        float* pS2  = (float*)(ws + O4_PS2);
        int*   pI1  = (int*)(ws + O4_PI1);

        vq_prep<<<256, 256, 0, stream>>>(cb, cbSw, c2);
        vq_mfma<4><<<dim3(256, 4), 256, 0, stream>>>(lat, cbSw, c2, pS1, pS2, pI1);
        vq_tail<4><<<256, 256, 0, stream>>>(lat, (const float*)cb, c2, pS1, pS2, pI1, out);
    } else {
        float* c2 = (float*)ws;
        vq_norms_fb<<<128, 256, 0, stream>>>(cb, c2);
        const size_t needSplit = 32768u + 2u * N_TOTAL * 4u + 2u * N_TOTAL * 4u + 64u;
        if (ws_size >= needSplit) {
            float* partS = (float*)(ws + 32768);
            int*   partI = (int*)(ws + 32768 + 2 * N_TOTAL * 4);
            dim3 grid(N_TOTAL / BM, 2);
            vq_fp32<<<grid, 256, 0, stream>>>(lat, cb, c2, (K_CODES / BN) / 2, out, partS, partI, 1);
            vq_merge_fb<<<N_TOTAL / 256, 256, 0, stream>>>(partS, partI, out);
        } else {
            dim3 grid(N_TOTAL / BM, 1);
            vq_fp32<<<grid, 256, 0, stream>>>(lat, cb, c2, K_CODES / BN, out, nullptr, nullptr, 0);
        }
    }
}

// Round 17
// 181.226 us; speedup vs baseline: 5.7735x; 5.7735x over previous
//
#include <hip/hip_runtime.h>
#include <stdint.h>

// VQ-VAE nearest-codebook index: N=32768 queries, D=64, K=8192 codes.
// FINAL (R21 = R19 revert): session best 182.3us (baseline 247.6, -26%).
// Phase A: bf16x3 MFMA (hi/lo split), argmax form (C-init = -0.5*||c||^2),
//          med3 second-best tracking, B direct L2->registers (LDS-free,
//          barrier-free; 1-step reg prefetch). 32 q/wave, 128 q/block,
//          split-K=8 grid (2048 blocks), launch_bounds (256,4).
// Plateau evidence: per-wave live state ~124 unified regs (60 arch VGPR +
//          accs/temps) => 4 waves/SIMD max spill-free residency.
//          (256,8)->VGPR32 and (256,6)->VGPR40 both spill-stormed (R18/R20:
//          FETCH/WRITE inflated 200x, 985-1268us). Residency was the only
//          lever that ever moved this kernel (R10 +26%, R12 +16%; nine
//          structural reorderings null). vq_mfma ~116us vs 50us MFMA floor;
//          non-mfma residue ~65us is fixed launch/harness envelope.
// Tail: fused merge(8 partials) + pruned exact re-solve + write.
//          EPS 0.008 > 2*delta = 6.2e-3 worst-case bf16x3 bound;
//          flag-and-repair validated absmax=0 across R6-R20.

#define N_TOTAL 32768
#define K_CODES 8192
#define EPS_GAP 0.008f

typedef __attribute__((ext_vector_type(4)))  float  floatx4;
typedef __attribute__((ext_vector_type(8)))  __bf16 bf16x8;

// ---- workspace layouts (bytes) ----
#define O_C2    0u          // 8192 f32
#define O_CBSW  32768u      // [256 kBlk][16 g][32 m][8 bf16] = 2 MB
// split-4 (legacy) partials:
#define O4_PS1  2129920u    // 4*32768 f32
#define O4_PS2  2654208u
#define O4_PI1  3178496u
#define WS_NEED4 4096256u
// split-8 partials:
#define O8_PS1  2129920u    // 8*32768 f32 = 1 MB
#define O8_PS2  3178496u
#define O8_PI1  4227072u
#define WS_NEED8 5275648u

__device__ __forceinline__ void load_lds16(const void* g, void* l) {
    __builtin_amdgcn_global_load_lds(
        (const __attribute__((address_space(1))) unsigned int*)g,
        (__attribute__((address_space(3))) unsigned int*)l, 16, 0, 0);
}

// ---- prep: split codebook into hi/lo bf16 fragments + row norms ----
// cbSw layout: [kBlk(32 codes)][g 0..7=hi dims g*8..g*8+7, 8..15=lo][m 0..31]
__global__ __launch_bounds__(256) void vq_prep(
    const float4* __restrict__ cb, uint4* __restrict__ cbSw,
    float* __restrict__ c2) {
    __shared__ float red[256];
    const int m = threadIdx.x & 31, g = threadIdx.x >> 5;
    const int rb = blockIdx.x;
    float4 a = cb[(size_t)(rb * 32 + m) * 16 + g * 2];
    float4 b = cb[(size_t)(rb * 32 + m) * 16 + g * 2 + 1];
    float x[8] = {a.x, a.y, a.z, a.w, b.x, b.y, b.z, b.w};
    bf16x8 hv, lv;
    float ss = 0.f;
#pragma unroll
    for (int i = 0; i < 8; ++i) {
        float v  = x[i];
        __bf16 hb = (__bf16)v;           // RNE
        float r  = v - (float)hb;
        hv[i] = hb;
        lv[i] = (__bf16)r;
        ss += v * v;
    }
    cbSw[(size_t)rb * 512 + g * 32 + m]       = __builtin_bit_cast(uint4, hv);
    cbSw[(size_t)rb * 512 + (8 + g) * 32 + m] = __builtin_bit_cast(uint4, lv);
    red[threadIdx.x] = ss;
    __syncthreads();
    if (threadIdx.x < 32) {
        float s = 0.f;
#pragma unroll
        for (int gg = 0; gg < 8; ++gg) s += red[threadIdx.x + 32 * gg];
        c2[rb * 32 + threadIdx.x] = s;
    }
}

// ---- phase A: 128 queries x (8192/NP) codes per block (split-K=NP) ----
// 16x16x32 MFMA. Wave: 32 queries (2 q-tiles). KP/16 flat steps; per step
// one 16-code col-tile: 4 B-frag uint4 loads (L2->reg) + 12 MFMA + track.
// C/D: col=lane&15, row=(lane>>4)*4+reg  [verified absmax=0, R10-R19].
// launch_bounds (256,4): VGPR cap 128; natural ~60 arch + accs fits, no spill.
template <int NP>
__global__ __launch_bounds__(256, 4) void vq_mfma(
    const float4* __restrict__ lat, const uint4* __restrict__ cbSw,
    const float* __restrict__ c2,
    float* __restrict__ pS1, float* __restrict__ pS2, int* __restrict__ pI1) {
    constexpr int KP = K_CODES / NP;
    constexpr int STEPS = KP / 16;
    const int tid = threadIdx.x;
    const int wr = tid >> 6, lane = tid & 63;
    const int c16 = lane & 15, h4 = lane >> 4;

    // A fragments for 2 q-tiles (split in-kernel; identical math to vq_prep).
    const int q0 = blockIdx.x * 128 + wr * 32 + c16;
    bf16x8 aH[2][2], aL[2][2];
#pragma unroll
    for (int qt = 0; qt < 2; ++qt)
#pragma unroll
    for (int c = 0; c < 2; ++c) {
        float4 v0 = lat[(size_t)(q0 + qt * 16) * 16 + c * 8 + h4 * 2];
        float4 v1 = lat[(size_t)(q0 + qt * 16) * 16 + c * 8 + h4 * 2 + 1];
        float x[8] = {v0.x, v0.y, v0.z, v0.w, v1.x, v1.y, v1.z, v1.w};
#pragma unroll
        for (int j = 0; j < 8; ++j) {
            float v  = x[j];
            __bf16 hb = (__bf16)v;
            aH[qt][c][j] = hb;
            aL[qt][c][j] = (__bf16)(v - (float)hb);
        }
    }

    // Track t1 = max(-s/2), t2 = second-max, i1 = argmax, per (qt, row).
    float t1[2][4], t2[2][4]; int i1[2][4];
#pragma unroll
    for (int qt = 0; qt < 2; ++qt)
#pragma unroll
    for (int r = 0; r < 4; ++r) { t1[qt][r] = -3e38f; t2[qt][r] = -3e38f; i1[qt][r] = 0; }

    const int kBase = blockIdx.y * KP;
    const uint4* sB = cbSw + ((size_t)(kBase >> 5) << 9);  // partition base
    const float* c2g = c2 + kBase + c16;   // per-lane c2 stream base
    const int fb = c16 + h4 * 32;          // frag offset within a step group

    // step s: stage = s>>2, T = s&3. uint4 group offset:
    //   off(s) = (s>>2)*1024 + (s&2)*256 + (s&1)*16
    // members at off+fb, +128, +256, +384 (bH0,bH1,bL0,bL1).
    // c2 scalar at c2g[(s>>2)*64 + (s&3)*16].

    // ---- prologue: load step-0 group ----
    uint4 b0, b1, b2, b3;
    {
        const uint4* p = sB + fb;
        b0 = p[0]; b1 = p[128]; b2 = p[256]; b3 = p[384];
    }
    float ccCur = c2g[0];

#pragma unroll 2
    for (int step = 0; step < STEPS; ++step) {
        // prefetch step+1 group (tail clamped: uniform pipeline, no branch)
        const int s1 = (step + 1 < STEPS) ? (step + 1) : (STEPS - 1);
        const uint4* p = sB + ((s1 >> 2) << 10) + ((s1 & 2) << 8) + ((s1 & 1) << 4) + fb;
        uint4 n0 = p[0], n1 = p[128], n2 = p[256], n3 = p[384];
        float ccN = c2g[((s1 >> 2) << 6) + ((s1 & 3) << 4)];

        const int col = kBase + ((step >> 2) << 6) + ((step & 3) << 4) + c16;
        const float nn = -0.5f * ccCur;   // prefetched last step: no chain-head stall
        bf16x8 bH0 = __builtin_bit_cast(bf16x8, b0);
        bf16x8 bH1 = __builtin_bit_cast(bf16x8, b1);
        bf16x8 bL0 = __builtin_bit_cast(bf16x8, b2);
        bf16x8 bL1 = __builtin_bit_cast(bf16x8, b3);

        __builtin_amdgcn_s_setprio(1);
        // 2 independent 6-MFMA chains (one per q-tile) sharing B regs.
#pragma unroll
        for (int qt = 0; qt < 2; ++qt) {
            floatx4 acc = {nn, nn, nn, nn};
            acc = __builtin_amdgcn_mfma_f32_16x16x32_bf16(aH[qt][0], bH0, acc, 0, 0, 0);
            acc = __builtin_amdgcn_mfma_f32_16x16x32_bf16(aH[qt][1], bH1, acc, 0, 0, 0);
            acc = __builtin_amdgcn_mfma_f32_16x16x32_bf16(aL[qt][0], bH0, acc, 0, 0, 0);
            acc = __builtin_amdgcn_mfma_f32_16x16x32_bf16(aL[qt][1], bH1, acc, 0, 0, 0);
            acc = __builtin_amdgcn_mfma_f32_16x16x32_bf16(aH[qt][0], bL0, acc, 0, 0, 0);
            acc = __builtin_amdgcn_mfma_f32_16x16x32_bf16(aH[qt][1], bL1, acc, 0, 0, 0);
            // acc[r] = dot - ||c||^2/2 = -s/2 : argmin(s) == argmax(acc).
#pragma unroll
            for (int r = 0; r < 4; ++r) {
                float a = acc[r];
                bool gt = a > t1[qt][r];
                t2[qt][r] = __builtin_amdgcn_fmed3f(a, t1[qt][r], t2[qt][r]);
                t1[qt][r] = fmaxf(t1[qt][r], a);
                i1[qt][r] = gt ? col : i1[qt][r];
            }
        }
        __builtin_amdgcn_s_setprio(0);

        b0 = n0; b1 = n1; b2 = n2; b3 = n3;   // unroll-2 renames these away
        ccCur = ccN;
    }

    // reduce (t1,i1,t2) across the 16 column-lanes of each row-group
#pragma unroll
    for (int mask = 1; mask <= 8; mask <<= 1) {
#pragma unroll
        for (int qt = 0; qt < 2; ++qt)
#pragma unroll
        for (int r = 0; r < 4; ++r) {
            float o1 = __shfl_xor(t1[qt][r], mask);
            float o2 = __shfl_xor(t2[qt][r], mask);
            int   oi = __shfl_xor(i1[qt][r], mask);
            float n2 = fmaxf(fmaxf(t2[qt][r], o2), fminf(t1[qt][r], o1));
            bool take = (o1 > t1[qt][r]) || (o1 == t1[qt][r] && oi < i1[qt][r]);
            t1[qt][r] = take ? o1 : t1[qt][r];
            i1[qt][r] = take ? oi : i1[qt][r];
            t2[qt][r] = n2;
        }
    }

    if (c16 == 0) {
        const int o0 = blockIdx.y * N_TOTAL;
#pragma unroll
        for (int qt = 0; qt < 2; ++qt) {
            const int qb = blockIdx.x * 128 + wr * 32 + qt * 16 + h4 * 4; // C/D rows
#pragma unroll
            for (int r = 0; r < 4; ++r) {
                pS1[o0 + qb + r] = -2.f * t1[qt][r];  // exact *2: order preserved
                pS2[o0 + qb + r] = -2.f * t2[qt][r];
                pI1[o0 + qb + r] = i1[qt][r];
            }
        }
    }
}

// ---- fused tail: merge NP partials + pruned exact re-solve + write ----
// Block owns 128 queries. Phase 1 (tid<128): merge, write provisional out,
// flag near-ties into LDS with a per-partition scan-mask. Phase 2: per
// flagged entry, all 256 threads cooperate -- scan partitions split
// KP/256 codes/thread; non-scan partitions' top-1 by threads 0..NP-1 --
// then LDS argmin-reduce (index tie-break) and direct out write.
template <int NP>
__global__ __launch_bounds__(256) void vq_tail(
    const float4* __restrict__ lat, const float* __restrict__ cbf,
    const float* __restrict__ c2,
    const float* __restrict__ pS1, const float* __restrict__ pS2,
    const int* __restrict__ pI1, int* __restrict__ out) {
    constexpr int KP = K_CODES / NP;
    __shared__ unsigned char fqv[132];   // local (in-block) flagged query ids
    __shared__ unsigned short fmk[132];  // scan masks (up to 8 bits)
    __shared__ int fcnt;
    __shared__ float qv[64];
    __shared__ float redS[256];
    __shared__ int   redI[256];

    const int tid = threadIdx.x;
    if (tid == 0) fcnt = 0;
    __syncthreads();

    if (tid < 128) {
        const int q = blockIdx.x * 128 + tid;
        float g1 = 3e38f, g2 = 3e38f;
        int   gi = 0x7FFFFFFF;
        float s2v[NP];
#pragma unroll
        for (int p = 0; p < NP; ++p) {
            float s1p = pS1[p * N_TOTAL + q];
            float s2p = pS2[p * N_TOTAL + q];
            int   i1p = pI1[p * N_TOTAL + q];
            s2v[p] = s2p;
            bool take = (s1p < g1) || (s1p == g1 && i1p < gi);
            g2 = fminf(g2, fminf(s2p, take ? g1 : s1p));
            if (take) { g1 = s1p; gi = i1p; }
        }
        out[q] = gi;
        if (g2 - g1 < EPS_GAP) {
            int msk = 0;
#pragma unroll
            for (int p = 0; p < NP; ++p)
                if (s2v[p] - g1 < EPS_GAP) msk |= (1 << p);
            int e = atomicAdd(&fcnt, 1);
            fqv[e] = (unsigned char)tid;
            fmk[e] = (unsigned short)msk;
        }
    }
    __syncthreads();

    const int ne = fcnt;
    for (int e = 0; e < ne; ++e) {
        const int lq = fqv[e];
        const int gq = blockIdx.x * 128 + lq;
        const int msk = fmk[e];
        if (tid < 16) {
            float4 v = lat[(size_t)gq * 16 + tid];
            *(float4*)&qv[tid * 4] = v;
        }
        __syncthreads();

        float best = 3e38f; int bi = 0x7FFFFFFF;
        // non-scan partitions: single-candidate exact eval by threads 0..NP-1
        if (tid < NP && !((msk >> tid) & 1)) {
            const int k = pI1[tid * N_TOTAL + gq];
            const float4* cp = (const float4*)&cbf[(size_t)k * 64];
            float dot = 0.f;
#pragma unroll
            for (int d4 = 0; d4 < 16; ++d4) {
                float4 cv = cp[d4];
                dot += qv[d4 * 4 + 0] * cv.x + qv[d4 * 4 + 1] * cv.y
                     + qv[d4 * 4 + 2] * cv.z + qv[d4 * 4 + 3] * cv.w;
            }
            float s = c2[k] - 2.f * dot;
            if (s < best || (s == best && k < bi)) { best = s; bi = k; }
        }
        // scan partitions: all 256 threads cooperate (KP/256 codes/thread)
#pragma unroll
        for (int p = 0; p < NP; ++p) if ((msk >> p) & 1) {
            for (int j = tid; j < KP; j += 256) {
                const int k = p * KP + j;
                const float4* cp = (const float4*)&cbf[(size_t)k * 64];
                float dot = 0.f;
#pragma unroll
                for (int d4 = 0; d4 < 16; ++d4) {
                    float4 cv = cp[d4];
                    dot += qv[d4 * 4 + 0] * cv.x + qv[d4 * 4 + 1] * cv.y
                         + qv[d4 * 4 + 2] * cv.z + qv[d4 * 4 + 3] * cv.w;
                }
                float s = c2[k] - 2.f * dot;
                if (s < best || (s == best && k < bi)) { best = s; bi = k; }
            }
        }
        // block argmin-reduce with index tie-break
        redS[tid] = best; redI[tid] = bi;
        __syncthreads();
        for (int s = 128; s > 0; s >>= 1) {
            if (tid < s) {
                float os = redS[tid + s]; int oi = redI[tid + s];
                if (os < redS[tid] || (os == redS[tid] && oi < redI[tid])) {
                    redS[tid] = os; redI[tid] = oi;
                }
            }
            __syncthreads();
        }
        if (tid == 0) out[gq] = redI[0];
        __syncthreads();   // protect qv/redS reuse next entry
    }
}

// ================= fallback: validated round-1 fp32 path =================
#define BM 128
#define BN 128
#define PAD 68

__global__ void vq_norms_fb(const float4* __restrict__ cb, float* __restrict__ c2) {
    int t = blockIdx.x * 256 + threadIdx.x;
    int r = t >> 2, p = t & 3;
    float s = 0.f;
#pragma unroll
    for (int i = 0; i < 4; ++i) {
        float4 v = cb[r * 16 + p * 4 + i];
        s += v.x * v.x + v.y * v.y + v.z * v.z + v.w * v.w;
    }
    s += __shfl_xor(s, 1);
    s += __shfl_xor(s, 2);
    if (p == 0) c2[r] = s;
}

__global__ __launch_bounds__(256) void vq_fp32(
    const float4* __restrict__ lat, const float4* __restrict__ cb,
    const float* __restrict__ c2, int ktPer,
    int* __restrict__ outIdx, float* __restrict__ partS, int* __restrict__ partI,
    int writePartial) {
    __shared__ float As[BM][PAD];
    __shared__ float Bsf[BN][PAD];
    __shared__ float c2s[BN];
    const int tid = threadIdx.x;
    const int tx = tid & 15;
    const int ty = tid >> 4;
    const int nBase = blockIdx.x * BM;
    const int kt0 = blockIdx.y * ktPer;
    const int ktN = kt0 + ktPer;
#pragma unroll
    for (int r = 0; r < 8; ++r) {
        int f = tid + 256 * r;
        int mm = f >> 4, d4 = f & 15;
        float4 v = lat[(size_t)(nBase + mm) * 16 + d4];
        *(float4*)&As[mm][d4 * 4] = v;
    }
    float best[8]; int bidx[8];
#pragma unroll
    for (int ii = 0; ii < 8; ++ii) { best[ii] = 3e38f; bidx[ii] = 0; }
    for (int kt = kt0; kt < ktN; ++kt) {
        const int kbase = kt * BN;
        __syncthreads();
#pragma unroll
        for (int r = 0; r < 8; ++r) {
            int f = tid + 256 * r;
            int k = f >> 4, d4 = f & 15;
            float4 v = cb[(size_t)(kbase + k) * 16 + d4];
            *(float4*)&Bsf[k][d4 * 4] = v;
        }
        if (tid < BN) c2s[tid] = c2[kbase + tid];
        __syncthreads();
        float acc[8][8];
#pragma unroll
        for (int ii = 0; ii < 8; ++ii)
#pragma unroll
            for (int jj = 0; jj < 8; ++jj) acc[ii][jj] = 0.f;
#pragma unroll 4
        for (int d4 = 0; d4 < 16; ++d4) {
            float4 a[8], b[8];
#pragma unroll
            for (int ii = 0; ii < 8; ++ii) a[ii] = *(const float4*)&As[tx + 16 * ii][d4 * 4];
#pragma unroll
            for (int jj = 0; jj < 8; ++jj) b[jj] = *(const float4*)&Bsf[ty + 16 * jj][d4 * 4];
#pragma unroll
            for (int ii = 0; ii < 8; ++ii)
#pragma unroll
                for (int jj = 0; jj < 8; ++jj)
                    acc[ii][jj] += a[ii].x * b[jj].x + a[ii].y * b[jj].y
                                 + a[ii].z * b[jj].z + a[ii].w * b[jj].w;
        }
#pragma unroll
        for (int jj = 0; jj < 8; ++jj) {
            int k = kbase + ty + 16 * jj;
            float cc = c2s[ty + 16 * jj];
#pragma unroll
            for (int ii = 0; ii < 8; ++ii) {
                float s = cc - 2.f * acc[ii][jj];
                if (s < best[ii]) { best[ii] = s; bidx[ii] = k; }
            }
        }
    }
    __syncthreads();
    float* redS = &As[0][0];
    int*   redI = (int*)&Bsf[0][0];
#pragma unroll
    for (int ii = 0; ii < 8; ++ii) {
        int mm = tx + 16 * ii;
        redS[ty * BM + mm] = best[ii];
        redI[ty * BM + mm] = bidx[ii];
    }
    __syncthreads();
    if (tid < BM) {
        int mm = tid;
        float bs = redS[mm]; int bi = redI[mm];
#pragma unroll
        for (int t = 1; t < 16; ++t) {
            float s = redS[t * BM + mm]; int i = redI[t * BM + mm];
            if (s < bs || (s == bs && i < bi)) { bs = s; bi = i; }
        }
        int n = nBase + mm;
        if (writePartial) { partS[blockIdx.y * N_TOTAL + n] = bs; partI[blockIdx.y * N_TOTAL + n] = bi; }
        else outIdx[n] = bi;
    }
}

__global__ void vq_merge_fb(const float* __restrict__ partS, const int* __restrict__ partI,
                            int* __restrict__ out) {
    int n = blockIdx.x * 256 + threadIdx.x;
    float s0 = partS[n], s1 = partS[N_TOTAL + n];
    int   i0 = partI[n], i1 = partI[N_TOTAL + n];
    out[n] = (s1 < s0) ? i1 : i0;
}

extern "C" void kernel_launch(void* const* d_in, const int* in_sizes, int n_in,
                              void* d_out, int out_size, void* d_ws, size_t ws_size,
                              hipStream_t stream) {
    const float4* lat = (const float4*)d_in[0];
    const float4* cb  = (const float4*)d_in[1];
    int* out = (int*)d_out;
    char* ws = (char*)d_ws;

    if (ws_size >= WS_NEED8) {
        float* c2   = (float*)(ws + O_C2);
        uint4* cbSw = (uint4*)(ws + O_CBSW);
        float* pS1  = (float*)(ws + O8_PS1);
        float* pS2  = (float*)(ws + O8_PS2);
        int*   pI1  = (int*)(ws + O8_PI1);

        vq_prep<<<256, 256, 0, stream>>>(cb, cbSw, c2);
        vq_mfma<8><<<dim3(256, 8), 256, 0, stream>>>(lat, cbSw, c2, pS1, pS2, pI1);
        vq_tail<8><<<256, 256, 0, stream>>>(lat, (const float*)cb, c2, pS1, pS2, pI1, out);
    } else if (ws_size >= WS_NEED4) {
        float* c2   = (float*)(ws + O_C2);
        uint4* cbSw = (uint4*)(ws + O_CBSW);
        float* pS1  = (float*)(ws + O4_PS1);
        float* pS2  = (float*)(ws + O4_PS2);
        int*   pI1  = (int*)(ws + O4_PI1);

        vq_prep<<<256, 256, 0, stream>>>(cb, cbSw, c2);
        vq_mfma<4><<<dim3(256, 4), 256, 0, stream>>>(lat, cbSw, c2, pS1, pS2, pI1);
        vq_tail<4><<<256, 256, 0, stream>>>(lat, (const float*)cb, c2, pS1, pS2, pI1, out);
    } else {
        float* c2 = (float*)ws;
        vq_norms_fb<<<128, 256, 0, stream>>>(cb, c2);
        const size_t needSplit = 32768u + 2u * N_TOTAL * 4u + 2u * N_TOTAL * 4u + 64u;
        if (ws_size >= needSplit) {
            float* partS = (float*)(ws + 32768);
            int*   partI = (int*)(ws + 32768 + 2 * N_TOTAL * 4);
            dim3 grid(N_TOTAL / BM, 2);
            vq_fp32<<<grid, 256, 0, stream>>>(lat, cb, c2, (K_CODES / BN) / 2, out, partS, partI, 1);
            vq_merge_fb<<<N_TOTAL / 256, 256, 0, stream>>>(partS, partI, out);
        } else {
            dim3 grid(N_TOTAL / BM, 1);
            vq_fp32<<<grid, 256, 0, stream>>>(lat, cb, c2, K_CODES / BN, out, nullptr, nullptr, 0);
        }
    }
}